// Round 2
// baseline (478.790 us; speedup 1.0000x reference)
//
#include <hip/hip_runtime.h>
#include <cstddef>

#define HH 16
#define TT 512
#define STG 16           // timesteps per LDS x-stage
#define NSTG (TT / STG)  // 32 stages
#define LOG2E 1.44269504088896340736f

typedef float v2f __attribute__((ext_vector_type(2)));
typedef float v4f __attribute__((ext_vector_type(4)));

static __device__ __forceinline__ float fexp2(float x){ return __builtin_amdgcn_exp2f(x); }
static __device__ __forceinline__ float frcp (float x){ return __builtin_amdgcn_rcpf(x); }
static __device__ __forceinline__ float frsq (float x){ return __builtin_amdgcn_rsqf(x); }

// tanh(c) = 2/(1+exp(-2c)) - 1 ; saturates correctly (rcp(inf)=0)
static __device__ __forceinline__ float ftanh(float c){
    return frcp(1.0f + fexp2(c * (-2.0f*LOG2E))) * 2.0f - 1.0f;
}

// broadcast within each quad of lanes (single v_mov_b32_dpp)
#if __has_builtin(__builtin_amdgcn_mov_dpp)
template<int CTRL>
static __device__ __forceinline__ float qb(float v){
    return __builtin_bit_cast(float,
        __builtin_amdgcn_mov_dpp(__builtin_bit_cast(int,v), CTRL, 0xF, 0xF, true));
}
#else
template<int CTRL>
static __device__ __forceinline__ float qb(float v){
    return __builtin_bit_cast(float,
        __builtin_amdgcn_update_dpp(0, __builtin_bit_cast(int,v), CTRL, 0xF, 0xF, true));
}
#endif

static __device__ __forceinline__ v2f pkfma(v2f a, v2f b, v2f c){
    return __builtin_elementwise_fma(a, b, c);  // -> v_pk_fma_f32
}

// accumulate a 16-float dot into two v2f partials (8 pk_fma)
static __device__ __forceinline__ void dot16_acc(const v4f* a, const v4f* w, v2f& s0, v2f& s1){
    s0 = pkfma(a[0].lo, w[0].lo, s0);  s1 = pkfma(a[0].hi, w[0].hi, s1);
    s0 = pkfma(a[1].lo, w[1].lo, s0);  s1 = pkfma(a[1].hi, w[1].hi, s1);
    s0 = pkfma(a[2].lo, w[2].lo, s0);  s1 = pkfma(a[2].hi, w[2].hi, s1);
    s0 = pkfma(a[3].lo, w[3].lo, s0);  s1 = pkfma(a[3].hi, w[3].hi, s1);
}

static __device__ __forceinline__ void ld4(v4f* dst, const float* p){
    const v4f* q = (const v4f*)p;
    dst[0] = q[0]; dst[1] = q[1]; dst[2] = q[2]; dst[3] = q[3];
}

// TWO batch elements per wave, as two independent scalar dependency chains
// interleaved in straight-line code. Lane l owns gate g=l&3 of hidden unit
// k=l>>2 for BOTH batches. Rationale:
//  * 4 identical waves/SIMD phase-lock and stall together on the h-broadcast
//    LDS round trip; an in-wave second chain fills those bubbles
//    deterministically.
//  * __launch_bounds__(256,2) lifts the VGPR cap to 256 so the whole live set
//    stays in arch VGPRs (the (256,4) build overflowed into AGPRs and paid
//    v_accvgpr copy traffic on the VALU pipe).
__global__ __launch_bounds__(256, 2) void lstm_fused_kernel(
    const float* __restrict__ x,
    const float* __restrict__ W_ih0, const float* __restrict__ W_hh0,
    const float* __restrict__ b_ih0, const float* __restrict__ b_hh0,
    const float* __restrict__ W_ih1, const float* __restrict__ W_hh1,
    const float* __restrict__ b_ih1, const float* __restrict__ b_hh1,
    const float* __restrict__ W_proj, const float* __restrict__ b_proj,
    const float* __restrict__ ln_g, const float* __restrict__ ln_b,
    float* __restrict__ out)
{
    const int lane = threadIdx.x & 63;
    const int wave = threadIdx.x >> 6;
    const int bA   = blockIdx.x * 8 + wave * 2;   // batch element A
    const int bB   = bA + 1;                      // batch element B

    const int g   = lane & 3;        // 0=i 1=f 2=g 3=o
    const int k   = lane >> 2;       // hidden unit 0..15
    const int row = g * HH + k;      // row in [4H,H] weights (PyTorch order)

    // per (wave,batch) LDS: two 256-float x-stages (ping-pong) + h1[16] + h2[16]
    __shared__ float sh[8 * 544];
    float* shA  = sh + (wave * 2 + 0) * 544;
    float* shB  = sh + (wave * 2 + 1) * 544;
    float* xb0A = shA;        float* xb0B = shB;
    float* xb1A = shA + 256;  float* xb1B = shB + 256;
    float* h1wA = shA + 512;  float* h1wB = shB + 512;
    float* h2wA = shA + 528;  float* h2wB = shB + 528;

    // activation input scale: sigmoid lanes -log2e, tanh(g) lane -2log2e.
    const bool  isg   = (g == 2);
    const float sc_in = isg ? (-2.0f * LOG2E) : (-LOG2E);

    // ---- weights into VGPRs as v4f, PRE-SCALED by sc_in (shared by A,B) ----
    v4f wih0[4], whh0[4], wih1[4], whh1[4];
#pragma unroll
    for (int q = 0; q < 4; ++q) {
        wih0[q] = ((const v4f*)(W_ih0 + row * HH))[q] * sc_in;
        whh0[q] = ((const v4f*)(W_hh0 + row * HH))[q] * sc_in;
        wih1[q] = ((const v4f*)(W_ih1 + row * HH))[q] * sc_in;
        whh1[q] = ((const v4f*)(W_hh1 + row * HH))[q] * sc_in;
    }
    const float bias0 = (b_ih0[row] + b_hh0[row]) * sc_in;
    const float bias1 = (b_ih1[row] + b_hh1[row]) * sc_in;

    const float* xgA = x + (size_t)bA * TT * HH;
    const float* xgB = x + (size_t)bB * TT * HH;

    // ================= prologue =================
    v4f xsA = *(const v4f*)(xgA + lane * 4);     // global stage 0
    v4f xsB = *(const v4f*)(xgB + lane * 4);
    *(v4f*)(xb0A + lane * 4) = xsA;              // LDS stage 0
    *(v4f*)(xb0B + lane * 4) = xsB;
    xsA = *(const v4f*)(xgA + 256 + lane * 4);   // prefetch global stage 1
    xsB = *(const v4f*)(xgB + 256 + lane * 4);

    v4f xaA[4], xaB[4];
    ld4(xaA, xb0A);                              // broadcast x(0)
    ld4(xaB, xb0B);

    float cs1A, cs2A = 0.0f;                     // cs = -2*log2e * c
    float cs1B, cs2B = 0.0f;
    v4f h1aA[4], h2aA[4], h1aB[4], h2aB[4];
#pragma unroll
    for (int q = 0; q < 4; ++q) { h2aA[q] = (v4f)(0.f); h2aB[q] = (v4f)(0.f); }

    // layer-1 step 0 (h1(-1) = 0: skip hh dot)
    {
        v2f p0A = {bias0, 0.f}, p1A = {0.f, 0.f};
        v2f p0B = {bias0, 0.f}, p1B = {0.f, 0.f};
        dot16_acc(xaA, wih0, p0A, p1A);
        dot16_acc(xaB, wih0, p0B, p1B);
        v2f psA = p0A + p1A;               v2f psB = p0B + p1B;
        float a1A = psA.x + psA.y;         float a1B = psB.x + psB.y;
        float r1A = frcp(1.0f + fexp2(a1A));
        float r1B = frcp(1.0f + fexp2(a1B));
        float i1A = qb<0x00>(r1A), g1A = qb<0xAA>(r1A), o1A = qb<0xFF>(r1A);
        float i1B = qb<0x00>(r1B), g1B = qb<0xAA>(r1B), o1B = qb<0xFF>(r1B);
        float gs1A = __builtin_fmaf(g1A, -4.0f*LOG2E, 2.0f*LOG2E);
        float gs1B = __builtin_fmaf(g1B, -4.0f*LOG2E, 2.0f*LOG2E);
        cs1A = i1A * gs1A;                 cs1B = i1B * gs1B;
        float h1nA = o1A * (frcp(1.0f + fexp2(cs1A)) * 2.0f - 1.0f);
        float h1nB = o1B * (frcp(1.0f + fexp2(cs1B)) * 2.0f - 1.0f);
        h1wA[k] = h1nA;                    h1wB[k] = h1nB;
        ld4(h1aA, h1wA);                   ld4(h1aB, h1wB);   // broadcast h1(0)
        ld4(xaA, xb0A + HH);               ld4(xaB, xb0B + HH); // broadcast x(1)
    }

    // ================= main loop =================
    // iter t: layer1 computes h1(t+1) [xa=x(t+1), h1a=h1(t)];
    //         layer2 computes h2(t)   [h1a=h1(t), h2a=h2(t-1)]
    for (int s = 0; s < NSTG; ++s) {
        float* curA = (s & 1) ? xb1A : xb0A;  float* nxtA = (s & 1) ? xb0A : xb1A;
        float* curB = (s & 1) ? xb1B : xb0B;  float* nxtB = (s & 1) ? xb0B : xb1B;

        *(v4f*)(nxtA + lane * 4) = xsA;       // LDS stage s+1
        *(v4f*)(nxtB + lane * 4) = xsB;
        const int sp = (s + 2 < NSTG) ? (s + 2) : (NSTG - 1);
        xsA = *(const v4f*)(xgA + (size_t)sp * 256 + lane * 4);  // prefetch s+2
        xsB = *(const v4f*)(xgB + (size_t)sp * 256 + lane * 4);

#pragma unroll
        for (int ti = 0; ti < STG; ++ti) {
            // ---- layer 1, step t+1 (both chains) ----
            v2f p0A = {bias0, 0.f}, p1A = {0.f, 0.f};
            v2f p0B = {bias0, 0.f}, p1B = {0.f, 0.f};
            dot16_acc(xaA, wih0, p0A, p1A);
            dot16_acc(xaB, wih0, p0B, p1B);
            dot16_acc(h1aA, whh0, p0A, p1A);
            dot16_acc(h1aB, whh0, p0B, p1B);
            v2f psA = p0A + p1A;              v2f psB = p0B + p1B;
            float a1A = psA.x + psA.y;        float a1B = psB.x + psB.y;
            float r1A = frcp(1.0f + fexp2(a1A));
            float r1B = frcp(1.0f + fexp2(a1B));
            float i1A = qb<0x00>(r1A), f1A = qb<0x55>(r1A);
            float g1A = qb<0xAA>(r1A), o1A = qb<0xFF>(r1A);
            float i1B = qb<0x00>(r1B), f1B = qb<0x55>(r1B);
            float g1B = qb<0xAA>(r1B), o1B = qb<0xFF>(r1B);
            float gs1A = __builtin_fmaf(g1A, -4.0f*LOG2E, 2.0f*LOG2E);
            float gs1B = __builtin_fmaf(g1B, -4.0f*LOG2E, 2.0f*LOG2E);
            cs1A = __builtin_fmaf(f1A, cs1A, i1A * gs1A);
            cs1B = __builtin_fmaf(f1B, cs1B, i1B * gs1B);
            float h1nA = o1A * (frcp(1.0f + fexp2(cs1A)) * 2.0f - 1.0f);
            float h1nB = o1B * (frcp(1.0f + fexp2(cs1B)) * 2.0f - 1.0f);
            h1wA[k] = h1nA;                   // publish h1(t+1)
            h1wB[k] = h1nB;

            // ---- layer 2 part A: h1(t) · W_ih1 (last use of h1a) ----
            v2f q0A = {bias1, 0.f}, q1A = {0.f, 0.f};
            v2f q0B = {bias1, 0.f}, q1B = {0.f, 0.f};
            dot16_acc(h1aA, wih1, q0A, q1A);
            dot16_acc(h1aB, wih1, q0B, q1B);

            ld4(h1aA, h1wA);                  // broadcast h1(t+1)  [next iter]
            ld4(h1aB, h1wB);
            // broadcast x(t+2) [next iter]; ti=14,15 cross into next stage
            // (ti is a compile-time constant after unrolling: no runtime select)
            ld4(xaA, (ti <= 13) ? (curA + (ti + 2) * HH) : (nxtA + (ti - 14) * HH));
            ld4(xaB, (ti <= 13) ? (curB + (ti + 2) * HH) : (nxtB + (ti - 14) * HH));

            // ---- layer 2 part B: h2(t-1) · W_hh1 ----
            dot16_acc(h2aA, whh1, q0A, q1A);
            dot16_acc(h2aB, whh1, q0B, q1B);
            v2f qsA = q0A + q1A;              v2f qsB = q0B + q1B;
            float a2A = qsA.x + qsA.y;        float a2B = qsB.x + qsB.y;
            float r2A = frcp(1.0f + fexp2(a2A));
            float r2B = frcp(1.0f + fexp2(a2B));
            float i2A = qb<0x00>(r2A), f2A = qb<0x55>(r2A);
            float g2A = qb<0xAA>(r2A), o2A = qb<0xFF>(r2A);
            float i2B = qb<0x00>(r2B), f2B = qb<0x55>(r2B);
            float g2B = qb<0xAA>(r2B), o2B = qb<0xFF>(r2B);
            float gs2A = __builtin_fmaf(g2A, -4.0f*LOG2E, 2.0f*LOG2E);
            float gs2B = __builtin_fmaf(g2B, -4.0f*LOG2E, 2.0f*LOG2E);
            cs2A = __builtin_fmaf(f2A, cs2A, i2A * gs2A);
            cs2B = __builtin_fmaf(f2B, cs2B, i2B * gs2B);
            float h2nA = o2A * (frcp(1.0f + fexp2(cs2A)) * 2.0f - 1.0f);
            float h2nB = o2B * (frcp(1.0f + fexp2(cs2B)) * 2.0f - 1.0f);
            h2wA[k] = h2nA;                   // publish h2(t)
            h2wB[k] = h2nB;
            ld4(h2aA, h2wA);                  // broadcast h2(t)    [next iter]
            ld4(h2aB, h2wB);
        }
    }

    // ---- epilogue: z = h2(T-1) @ W_proj^T + b_proj ; LayerNorm ; tanh ----
    const int u = lane & 15;   // output unit (replicated x4 across the wave)
    v4f wp[4];
#pragma unroll
    for (int q = 0; q < 4; ++q) wp[q] = ((const v4f*)(W_proj + u * HH))[q];
    const float lg = ln_g[u], lb = ln_b[u], bp = b_proj[u];

    v2f z0A = {0.f, 0.f}, z1A = {0.f, 0.f};
    v2f z0B = {0.f, 0.f}, z1B = {0.f, 0.f};
    dot16_acc(h2aA, wp, z0A, z1A);
    dot16_acc(h2aB, wp, z0B, z1B);
    v2f zsA = z0A + z1A;                 v2f zsB = z0B + z1B;
    float zA = bp + zsA.x + zsA.y;       float zB = bp + zsB.x + zsB.y;

    // stats across the 16-lane group (xor masks 1,2,4,8 stay in-group)
    float sA = zA, sB = zB;
    sA += __shfl_xor(sA, 1); sB += __shfl_xor(sB, 1);
    sA += __shfl_xor(sA, 2); sB += __shfl_xor(sB, 2);
    sA += __shfl_xor(sA, 4); sB += __shfl_xor(sB, 4);
    sA += __shfl_xor(sA, 8); sB += __shfl_xor(sB, 8);
    const float muA = sA * (1.0f / 16.0f);
    const float muB = sB * (1.0f / 16.0f);

    const float dA = zA - muA;           const float dB = zB - muB;
    float qA = dA * dA, qB = dB * dB;
    qA += __shfl_xor(qA, 1); qB += __shfl_xor(qB, 1);
    qA += __shfl_xor(qA, 2); qB += __shfl_xor(qB, 2);
    qA += __shfl_xor(qA, 4); qB += __shfl_xor(qB, 4);
    qA += __shfl_xor(qA, 8); qB += __shfl_xor(qB, 8);
    const float varA = qA * (1.0f / 16.0f);
    const float varB = qB * (1.0f / 16.0f);

    const float yA = dA * frsq(varA + 1e-5f) * lg + lb;
    const float yB = dB * frsq(varB + 1e-5f) * lg + lb;
    const float resA = ftanh(yA);
    const float resB = ftanh(yB);

    if (lane < 16) {
        out[(size_t)bA * HH + lane] = resA;
        out[(size_t)bB * HH + lane] = resB;
    }
}

extern "C" void kernel_launch(void* const* d_in, const int* in_sizes, int n_in,
                              void* d_out, int out_size, void* d_ws, size_t ws_size,
                              hipStream_t stream) {
    const float* x      = (const float*)d_in[0];
    const float* W_ih0  = (const float*)d_in[1];
    const float* W_hh0  = (const float*)d_in[2];
    const float* b_ih0  = (const float*)d_in[3];
    const float* b_hh0  = (const float*)d_in[4];
    const float* W_ih1  = (const float*)d_in[5];
    const float* W_hh1  = (const float*)d_in[6];
    const float* b_ih1  = (const float*)d_in[7];
    const float* b_hh1  = (const float*)d_in[8];
    const float* W_proj = (const float*)d_in[9];
    const float* b_proj = (const float*)d_in[10];
    const float* ln_g   = (const float*)d_in[11];
    const float* ln_b   = (const float*)d_in[12];
    float* out = (float*)d_out;

    const int B = in_sizes[0] / (TT * HH);   // 4096
    dim3 grid(B / 8), block(256);            // one wave per TWO batch elements
    hipLaunchKernelGGL(lstm_fused_kernel, grid, block, 0, stream,
                       x, W_ih0, W_hh0, b_ih0, b_hh0,
                       W_ih1, W_hh1, b_ih1, b_hh1,
                       W_proj, b_proj, ln_g, ln_b, out);
}